// Round 5
// baseline (398.123 us; speedup 1.0000x reference)
//
#include <hip/hip_runtime.h>

#define H    128
#define WP   130
#define BPF  516           // border pixels per face image
#define TBLN 3096          // 6 * 516
#define BAND 32            // output rows per block (bands 0-3); band 4 = rows 128-129

// Face order: back(0), down(1), front(2), left(3), right(4), top(5)
__constant__ int c_R[6][9] = {
  {-1,0,0,  0,1,0,  0,0,-1},
  { 1,0,0,  0,0,-1, 0,1,0 },
  { 1,0,0,  0,1,0,  0,0,1 },
  { 0,0,1,  0,1,0, -1,0,0 },
  { 0,0,-1, 0,1,0,  1,0,0 },
  { 1,0,0,  0,0,1,  0,-1,0},
};
// NEIGHBORS[face][side], side order: up(0), down(1), left(2), right(3)
__constant__ int c_conn[6][4] = {
  {5,1,4,3}, {2,0,3,4}, {5,1,3,4}, {5,1,0,2}, {5,1,2,0}, {0,2,3,4},
};

#define INV_FP (65.0f / 4128.0f)

// ---------- kernel A: build border table (3096 entries) ------------------
__global__ void __launch_bounds__(256)
border_table_kernel(int* __restrict__ tb_face, int4* __restrict__ tb_idx,
                    float4* __restrict__ tb_w) {
  int t = blockIdx.x * 256 + threadIdx.x;
  if (t >= TBLN) return;
  int face = t / BPF;
  int k    = t - face * BPF;

  int r, c;
  if (k < 130)      { r = 0;        c = k; }
  else if (k < 260) { r = WP - 1;   c = k - 130; }
  else if (k < 388) { r = k - 259;  c = 0; }
  else              { r = k - 387;  c = WP - 1; }

  int fs = -1;
  int4  idx = make_int4(0, 0, 0, 0);
  float4 w  = make_float4(0.f, 0.f, 0.f, 0.f);

  int cand[2]; int nc = 0;
  if (c == WP - 1) cand[nc++] = 3;
  if (c == 0)      cand[nc++] = 2;
  if (r == WP - 1) cand[nc++] = 1;
  if (r == 0)      cand[nc++] = 0;

  float uc = ((float)c - 64.5f) * INV_FP;
  float ur = ((float)r - 64.5f) * INV_FP;

  for (int kk = 0; kk < nc; ++kk) {
    int s  = cand[kk];
    int cf = c_conn[face][s];
    const int* Rc = c_R[cf];
    const int* Rf = c_R[face];
    float g[3];
    #pragma unroll
    for (int i = 0; i < 3; ++i) {
      float acc = 0.0f;
      #pragma unroll
      for (int j = 0; j < 3; ++j) {
        int rr = Rc[i*3+0]*Rf[j*3+0] + Rc[i*3+1]*Rf[j*3+1] + Rc[i*3+2]*Rf[j*3+2];
        float dj = (j == 0) ? uc : (j == 1) ? ur : 1.0f;
        acc += (float)rr * dj;
      }
      g[i] = acc;
    }
    float x = g[0] / g[2];
    float y = g[1] / g[2];
    if (fabsf(x) <= 1.01f && fabsf(y) <= 1.01f) {
      x = fminf(fmaxf(x, -1.0f), 1.0f);
      y = fminf(fmaxf(y, -1.0f), 1.0f);
      float xp = (x + 1.0f) * 0.5f * (float)(H - 1);
      float yp = (y + 1.0f) * 0.5f * (float)(H - 1);
      float x0 = floorf(xp), y0 = floorf(yp);
      float wx = xp - x0,    wy = yp - y0;
      int x0i = min(max((int)x0, 0), H - 1);
      int x1i = min(x0i + 1, H - 1);
      int y0i = min(max((int)y0, 0), H - 1);
      int y1i = min(y0i + 1, H - 1);
      fs  = cf;
      idx = make_int4(y0i * H + x0i, y0i * H + x1i, y1i * H + x0i, y1i * H + x1i);
      w   = make_float4((1.f - wx) * (1.f - wy), wx * (1.f - wy),
                        (1.f - wx) * wy,         wx * wy);
      break;
    }
  }
  tb_face[t] = fs;
  tb_idx[t]  = idx;
  tb_w[t]    = w;
}

// ---------- kernel B: fused band kernel ----------------------------------
// Block = (band, img). Bands 0-3: 32 output rows (1040 quads); band 4:
// rows 128-129 (65 quads). Stage needed input rows in LDS via aligned
// float4 loads; emit aligned float4 stores; border elements via table.
__global__ void __launch_bounds__(256)
fused_pad_kernel(const float* __restrict__ in, float4* __restrict__ out4,
                 const int* __restrict__ tb_face,
                 const int4* __restrict__ tb_idx,
                 const float4* __restrict__ tb_w) {
  __shared__ float lds[BAND * H];        // 16 KB
  const unsigned band = blockIdx.x;      // 0..4
  const unsigned img  = blockIdx.y;      // 0..6143
  const unsigned tid  = threadIdx.x;

  const unsigned r0   = band * BAND;                 // 0,32,64,96,128
  const unsigned ir0  = (r0 == 0u) ? 0u : r0 - 1u;   // first staged input row
  const unsigned rmax = (r0 + BAND - 1u > 128u) ? 128u : (r0 + BAND - 1u);
  const unsigned nr   = rmax - ir0;                  // staged input rows

  // ---- stage: input rows [ir0, ir0+nr) -> LDS, aligned float4 ----
  const float4* src4 = (const float4*)in + ((size_t)img << 12) + (size_t)ir0 * 32u;
  float4* lds4 = (float4*)lds;
  const unsigned nq_in = nr * 32u;                   // <= 1024
  for (unsigned q = tid; q < nq_in; q += 256u) lds4[q] = src4[q];
  __syncthreads();

  // uniform per-image constants
  const unsigned n    = img >> 8;
  const unsigned ch   = img & 255u;
  const unsigned rep  = n / 6u;
  const unsigned face = n - rep * 6u;

  const unsigned nq    = (band == 4u) ? 65u : (BAND * WP / 4u);  // 1040 or 65
  const unsigned qbase = r0 * WP / 4u;               // band start is quad-aligned

  for (unsigned ql = tid; ql < nq; ql += 256u) {
    unsigned p = (qbase + ql) << 2;                  // element offset in image
    unsigned r = p / 130u;                           // magic-mul
    unsigned c = p - r * 130u;
    float vals[4];
    #pragma unroll
    for (int j = 0; j < 4; ++j) {
      float v;
      if ((r - 1u) < 128u && (c - 1u) < 128u) {
        v = lds[(r - 1u - ir0) * H + (c - 1u)];
      } else {
        unsigned tk = (r == 0u)   ? c
                    : (r == 129u) ? (130u + c)
                    : (c == 0u)   ? (259u + r)
                    :               (387u + r);
        unsigned ti = face * (unsigned)BPF + tk;
        int fs = tb_face[ti];
        v = 0.0f;
        if (fs >= 0) {
          int4   id = tb_idx[ti];
          float4 w  = tb_w[ti];
          const float* s = in +
              ((size_t)(((rep * 6u + (unsigned)fs) << 8) + ch) << 14);
          v = w.x * s[id.x] + w.y * s[id.y] + w.z * s[id.z] + w.w * s[id.w];
        }
      }
      vals[j] = v;
      if (++c == 130u) { c = 0u; ++r; }
    }
    out4[(size_t)img * 4225u + qbase + ql] =
        make_float4(vals[0], vals[1], vals[2], vals[3]);
  }
}

// ---------- fallback (round-2 kernels) if d_ws unavailable ---------------
__global__ void __launch_bounds__(256)
interior_kernel(const float4* __restrict__ in4, float* __restrict__ out) {
  unsigned t = blockIdx.x * 256u + threadIdx.x;
  unsigned c4  = t & 31u;
  unsigned r   = (t >> 5) & 127u;
  unsigned img = t >> 12;
  float4 v = in4[t];
  unsigned o = img * 16900u + (r + 1u) * 130u + 1u + (c4 << 2);
  out[o] = v.x; out[o + 1] = v.y; out[o + 2] = v.z; out[o + 3] = v.w;
}

__global__ void __launch_bounds__(256)
border_kernel(const float* __restrict__ in, float* __restrict__ out) {
  unsigned tid = blockIdx.x * 256u + threadIdx.x;
  const unsigned total = 6144u * 516u;
  if (tid >= total) return;
  unsigned img = tid / 516u;
  unsigned k   = tid - img * 516u;
  int r, c;
  if (k < 130u)      { r = 0;               c = (int)k; }
  else if (k < 260u) { r = WP - 1;          c = (int)(k - 130u); }
  else if (k < 388u) { r = (int)(k - 259u); c = 0; }
  else               { r = (int)(k - 387u); c = WP - 1; }
  int n = (int)(img >> 8), ch = (int)(img & 255u);
  int face = n % 6, rep = n / 6;
  float v = 0.0f;
  int cand[2]; int nc = 0;
  if (c == WP - 1) cand[nc++] = 3;
  if (c == 0)      cand[nc++] = 2;
  if (r == WP - 1) cand[nc++] = 1;
  if (r == 0)      cand[nc++] = 0;
  float uc = ((float)c - 64.5f) * INV_FP;
  float ur = ((float)r - 64.5f) * INV_FP;
  for (int kk = 0; kk < nc; ++kk) {
    int s = cand[kk], cf = c_conn[face][s];
    const int* Rc = c_R[cf]; const int* Rf = c_R[face];
    float g[3];
    #pragma unroll
    for (int i = 0; i < 3; ++i) {
      float acc = 0.0f;
      #pragma unroll
      for (int j = 0; j < 3; ++j) {
        int rr = Rc[i*3+0]*Rf[j*3+0] + Rc[i*3+1]*Rf[j*3+1] + Rc[i*3+2]*Rf[j*3+2];
        float dj = (j == 0) ? uc : (j == 1) ? ur : 1.0f;
        acc += (float)rr * dj;
      }
      g[i] = acc;
    }
    float x = g[0] / g[2], y = g[1] / g[2];
    if (fabsf(x) <= 1.01f && fabsf(y) <= 1.01f) {
      x = fminf(fmaxf(x, -1.0f), 1.0f);
      y = fminf(fmaxf(y, -1.0f), 1.0f);
      const float* src = in + ((size_t)((rep * 6 + cf) * 256 + ch)) * H * H;
      float xp = (x + 1.0f) * 0.5f * (float)(H - 1);
      float yp = (y + 1.0f) * 0.5f * (float)(H - 1);
      float x0 = floorf(xp), y0 = floorf(yp);
      float wx = xp - x0, wy = yp - y0;
      int x0i = min(max((int)x0, 0), H - 1);
      int x1i = min(x0i + 1, H - 1);
      int y0i = min(max((int)y0, 0), H - 1);
      int y1i = min(y0i + 1, H - 1);
      v = src[y0i*H+x0i]*(1.f-wx)*(1.f-wy) + src[y0i*H+x1i]*wx*(1.f-wy)
        + src[y1i*H+x0i]*(1.f-wx)*wy       + src[y1i*H+x1i]*wx*wy;
      break;
    }
  }
  out[(unsigned)img * 16900u + (unsigned)r * 130u + (unsigned)c] = v;
}

extern "C" void kernel_launch(void* const* d_in, const int* in_sizes, int n_in,
                              void* d_out, int out_size, void* d_ws, size_t ws_size,
                              hipStream_t stream) {
  (void)in_sizes; (void)n_in; (void)out_size;
  const float* in = (const float*)d_in[0];
  float* out = (float*)d_out;

  const size_t need = (size_t)TBLN * (4 + 16 + 16);   // 111,456 B
  if (d_ws != nullptr && ws_size >= need) {
    int*    tb_face = (int*)d_ws;
    int4*   tb_idx  = (int4*)(tb_face + TBLN);
    float4* tb_w    = (float4*)(tb_idx + TBLN);
    border_table_kernel<<<(TBLN + 255) / 256, 256, 0, stream>>>(tb_face, tb_idx, tb_w);

    dim3 grid(5, 6144);   // 5 bands x 6144 images = 30720 blocks
    fused_pad_kernel<<<grid, 256, 0, stream>>>(in, (float4*)out,
                                               tb_face, tb_idx, tb_w);
  } else {
    interior_kernel<<<98304, 256, 0, stream>>>((const float4*)in, out);
    const unsigned btotal = 6144u * 516u;
    border_kernel<<<(btotal + 255u) / 256u, 256, 0, stream>>>(in, out);
  }
}

// Round 6
// 299.569 us; speedup vs baseline: 1.3290x; 1.3290x over previous
//
#include <hip/hip_runtime.h>

#define H    128
#define WP   130
#define BPF  516           // border pixels per face image
#define TBLN 3096          // 6 * 516

// Face order: back(0), down(1), front(2), left(3), right(4), top(5)
__constant__ int c_R[6][9] = {
  {-1,0,0,  0,1,0,  0,0,-1},
  { 1,0,0,  0,0,-1, 0,1,0 },
  { 1,0,0,  0,1,0,  0,0,1 },
  { 0,0,1,  0,1,0, -1,0,0 },
  { 0,0,-1, 0,1,0,  1,0,0 },
  { 1,0,0,  0,0,1,  0,-1,0},
};
// NEIGHBORS[face][side], side order: up(0), down(1), left(2), right(3)
__constant__ int c_conn[6][4] = {
  {5,1,4,3}, {2,0,3,4}, {5,1,3,4}, {5,1,0,2}, {5,1,2,0}, {0,2,3,4},
};

#define INV_FP (65.0f / 4128.0f)

// ---------- kernel A: build border table (3096 entries) ------------------
__global__ void __launch_bounds__(256)
border_table_kernel(int* __restrict__ tb_face, int4* __restrict__ tb_idx,
                    float4* __restrict__ tb_w) {
  int t = blockIdx.x * 256 + threadIdx.x;
  if (t >= TBLN) return;
  int face = t / BPF;
  int k    = t - face * BPF;

  int r, c;
  if (k < 130)      { r = 0;        c = k; }
  else if (k < 260) { r = WP - 1;   c = k - 130; }
  else if (k < 388) { r = k - 259;  c = 0; }
  else              { r = k - 387;  c = WP - 1; }

  int fs = -1;
  int4  idx = make_int4(0, 0, 0, 0);
  float4 w  = make_float4(0.f, 0.f, 0.f, 0.f);

  int cand[2]; int nc = 0;
  if (c == WP - 1) cand[nc++] = 3;
  if (c == 0)      cand[nc++] = 2;
  if (r == WP - 1) cand[nc++] = 1;
  if (r == 0)      cand[nc++] = 0;

  float uc = ((float)c - 64.5f) * INV_FP;
  float ur = ((float)r - 64.5f) * INV_FP;

  for (int kk = 0; kk < nc; ++kk) {
    int s  = cand[kk];
    int cf = c_conn[face][s];
    const int* Rc = c_R[cf];
    const int* Rf = c_R[face];
    float g[3];
    #pragma unroll
    for (int i = 0; i < 3; ++i) {
      float acc = 0.0f;
      #pragma unroll
      for (int j = 0; j < 3; ++j) {
        int rr = Rc[i*3+0]*Rf[j*3+0] + Rc[i*3+1]*Rf[j*3+1] + Rc[i*3+2]*Rf[j*3+2];
        float dj = (j == 0) ? uc : (j == 1) ? ur : 1.0f;
        acc += (float)rr * dj;
      }
      g[i] = acc;
    }
    float x = g[0] / g[2];
    float y = g[1] / g[2];
    if (fabsf(x) <= 1.01f && fabsf(y) <= 1.01f) {
      x = fminf(fmaxf(x, -1.0f), 1.0f);
      y = fminf(fmaxf(y, -1.0f), 1.0f);
      float xp = (x + 1.0f) * 0.5f * (float)(H - 1);
      float yp = (y + 1.0f) * 0.5f * (float)(H - 1);
      float x0 = floorf(xp), y0 = floorf(yp);
      float wx = xp - x0,    wy = yp - y0;
      int x0i = min(max((int)x0, 0), H - 1);
      int x1i = min(x0i + 1, H - 1);
      int y0i = min(max((int)y0, 0), H - 1);
      int y1i = min(y0i + 1, H - 1);
      fs  = cf;
      idx = make_int4(y0i * H + x0i, y0i * H + x1i, y1i * H + x0i, y1i * H + x1i);
      w   = make_float4((1.f - wx) * (1.f - wy), wx * (1.f - wy),
                        (1.f - wx) * wy,         wx * wy);
      break;
    }
  }
  tb_face[t] = fs;
  tb_idx[t]  = idx;
  tb_w[t]    = w;
}

// ---------- kernel B: row-pair bulk kernel (93.9% of output) -------------
// Output rows pair as (2m, 2m+1) = 65 aligned quads [65m, 65m+65).
// Clean quads q in {1..31} (row 2m, input shift 3) and {33..63} (row 2m+1,
// shift 1) both read aligned input quads ib = 64m + q - 33 and ib+1.
// m in 1..63 full; m=0 odd half only (row 1); m=64 even half only (row 128).
// Per thread: 2 coalesced float4 loads + lane select + 1 coalesced store.
__global__ void __launch_bounds__(256)
pairs_kernel(const float4* __restrict__ in4, float4* __restrict__ out4) {
  unsigned t   = blockIdx.x * 256u + threadIdx.x;   // grid.x=16 -> t in [0,4096)
  unsigned img = blockIdx.y;
  if (t >= 3968u) return;                           // 64 * 62
  unsigned j   = t / 62u;                           // 0..63 (magic-mul)
  unsigned qp  = t - j * 62u;                       // 0..61
  unsigned m   = (j == 0u && qp < 31u) ? 64u : j;   // remap to row-128 half
  unsigned odd = (qp >= 31u) ? 1u : 0u;             // odd row of the pair
  unsigned q   = qp + 1u + odd;                     // 1..31 or 33..63
  unsigned ib  = (m << 6) + q - 33u;                // 0..4094

  const float4* base = in4 + ((size_t)img << 12);
  float4 A = base[ib];
  float4 B = base[ib + 1u];
  float4 o = odd ? make_float4(A.y, A.z, A.w, B.x)
                 : make_float4(A.w, B.x, B.y, B.z);
  out4[(size_t)img * 4225u + 65u * m + q] = o;
}

// ---------- kernel C: edge quads (257 per image) -------------------------
// Pair 0 quads {0..32, 64}, pair 64 quads {0, 32..64}, pairs 1..63 quads
// {0, 32, 64}. Per element: interior -> scalar load, border -> table.
__global__ void __launch_bounds__(320)
edge_kernel(const float* __restrict__ in, float4* __restrict__ out4,
            const int* __restrict__ tb_face,
            const int4* __restrict__ tb_idx,
            const float4* __restrict__ tb_w) {
  unsigned k   = threadIdx.x;
  unsigned img = blockIdx.x;
  if (k >= 257u) return;

  unsigned qk;
  if (k < 33u)       qk = k;                        // pair 0: q 0..32
  else if (k == 33u) qk = 64u;                      // pair 0: q 64
  else if (k == 34u) qk = 4160u;                    // pair 64: q 0
  else if (k < 68u)  qk = 4192u + (k - 35u);        // pair 64: q 32..64
  else {
    unsigned jj = k - 68u;                          // 0..188
    unsigned mm = 1u + jj / 3u;                     // 1..63
    unsigned w  = jj - 3u * (jj / 3u);              // 0,1,2
    qk = 65u * mm + ((w == 0u) ? 0u : (w == 1u) ? 32u : 64u);
  }

  unsigned n    = img >> 8;
  unsigned ch   = img & 255u;
  unsigned rep  = n / 6u;
  unsigned face = n - rep * 6u;

  unsigned p = qk << 2;
  unsigned r = p / 130u;
  unsigned c = p - r * 130u;
  float vals[4];
  #pragma unroll
  for (int jj = 0; jj < 4; ++jj) {
    float v;
    if ((r - 1u) < 128u && (c - 1u) < 128u) {
      v = in[(img << 14) + ((r - 1u) << 7) + (c - 1u)];
    } else {
      unsigned tk = (r == 0u)   ? c
                  : (r == 129u) ? (130u + c)
                  : (c == 0u)   ? (259u + r)
                  :               (387u + r);
      unsigned ti = face * (unsigned)BPF + tk;
      int fs = tb_face[ti];
      v = 0.0f;
      if (fs >= 0) {
        int4   id = tb_idx[ti];
        float4 w  = tb_w[ti];
        const float* s = in +
            ((size_t)(((rep * 6u + (unsigned)fs) << 8) + ch) << 14);
        v = w.x * s[id.x] + w.y * s[id.y] + w.z * s[id.z] + w.w * s[id.w];
      }
    }
    vals[jj] = v;
    if (++c == 130u) { c = 0u; ++r; }
  }
  out4[(size_t)img * 4225u + qk] = make_float4(vals[0], vals[1], vals[2], vals[3]);
}

// ---------- fallback (round-2 kernels) if d_ws unavailable ---------------
__global__ void __launch_bounds__(256)
interior_kernel(const float4* __restrict__ in4, float* __restrict__ out) {
  unsigned t = blockIdx.x * 256u + threadIdx.x;
  unsigned c4  = t & 31u;
  unsigned r   = (t >> 5) & 127u;
  unsigned img = t >> 12;
  float4 v = in4[t];
  unsigned o = img * 16900u + (r + 1u) * 130u + 1u + (c4 << 2);
  out[o] = v.x; out[o + 1] = v.y; out[o + 2] = v.z; out[o + 3] = v.w;
}

__global__ void __launch_bounds__(256)
border_kernel(const float* __restrict__ in, float* __restrict__ out) {
  unsigned tid = blockIdx.x * 256u + threadIdx.x;
  const unsigned total = 6144u * 516u;
  if (tid >= total) return;
  unsigned img = tid / 516u;
  unsigned k   = tid - img * 516u;
  int r, c;
  if (k < 130u)      { r = 0;               c = (int)k; }
  else if (k < 260u) { r = WP - 1;          c = (int)(k - 130u); }
  else if (k < 388u) { r = (int)(k - 259u); c = 0; }
  else               { r = (int)(k - 387u); c = WP - 1; }
  int n = (int)(img >> 8), ch = (int)(img & 255u);
  int face = n % 6, rep = n / 6;
  float v = 0.0f;
  int cand[2]; int nc = 0;
  if (c == WP - 1) cand[nc++] = 3;
  if (c == 0)      cand[nc++] = 2;
  if (r == WP - 1) cand[nc++] = 1;
  if (r == 0)      cand[nc++] = 0;
  float uc = ((float)c - 64.5f) * INV_FP;
  float ur = ((float)r - 64.5f) * INV_FP;
  for (int kk = 0; kk < nc; ++kk) {
    int s = cand[kk], cf = c_conn[face][s];
    const int* Rc = c_R[cf]; const int* Rf = c_R[face];
    float g[3];
    #pragma unroll
    for (int i = 0; i < 3; ++i) {
      float acc = 0.0f;
      #pragma unroll
      for (int j = 0; j < 3; ++j) {
        int rr = Rc[i*3+0]*Rf[j*3+0] + Rc[i*3+1]*Rf[j*3+1] + Rc[i*3+2]*Rf[j*3+2];
        float dj = (j == 0) ? uc : (j == 1) ? ur : 1.0f;
        acc += (float)rr * dj;
      }
      g[i] = acc;
    }
    float x = g[0] / g[2], y = g[1] / g[2];
    if (fabsf(x) <= 1.01f && fabsf(y) <= 1.01f) {
      x = fminf(fmaxf(x, -1.0f), 1.0f);
      y = fminf(fmaxf(y, -1.0f), 1.0f);
      const float* src = in + ((size_t)((rep * 6 + cf) * 256 + ch)) * H * H;
      float xp = (x + 1.0f) * 0.5f * (float)(H - 1);
      float yp = (y + 1.0f) * 0.5f * (float)(H - 1);
      float x0 = floorf(xp), y0 = floorf(yp);
      float wx = xp - x0, wy = yp - y0;
      int x0i = min(max((int)x0, 0), H - 1);
      int x1i = min(x0i + 1, H - 1);
      int y0i = min(max((int)y0, 0), H - 1);
      int y1i = min(y0i + 1, H - 1);
      v = src[y0i*H+x0i]*(1.f-wx)*(1.f-wy) + src[y0i*H+x1i]*wx*(1.f-wy)
        + src[y1i*H+x0i]*(1.f-wx)*wy       + src[y1i*H+x1i]*wx*wy;
      break;
    }
  }
  out[(unsigned)img * 16900u + (unsigned)r * 130u + (unsigned)c] = v;
}

extern "C" void kernel_launch(void* const* d_in, const int* in_sizes, int n_in,
                              void* d_out, int out_size, void* d_ws, size_t ws_size,
                              hipStream_t stream) {
  (void)in_sizes; (void)n_in; (void)out_size;
  const float* in = (const float*)d_in[0];
  float* out = (float*)d_out;

  const size_t need = (size_t)TBLN * (4 + 16 + 16);   // 111,456 B
  if (d_ws != nullptr && ws_size >= need) {
    int*    tb_face = (int*)d_ws;
    int4*   tb_idx  = (int4*)(tb_face + TBLN);
    float4* tb_w    = (float4*)(tb_idx + TBLN);
    border_table_kernel<<<(TBLN + 255) / 256, 256, 0, stream>>>(tb_face, tb_idx, tb_w);

    dim3 grid(16, 6144);   // 16*256 = 4096 threads cover 3968 clean quads/img
    pairs_kernel<<<grid, 256, 0, stream>>>((const float4*)in, (float4*)out);

    edge_kernel<<<6144, 320, 0, stream>>>(in, (float4*)out,
                                          tb_face, tb_idx, tb_w);
  } else {
    interior_kernel<<<98304, 256, 0, stream>>>((const float4*)in, out);
    const unsigned btotal = 6144u * 516u;
    border_kernel<<<(btotal + 255u) / 256u, 256, 0, stream>>>(in, out);
  }
}

// Round 7
// 240.770 us; speedup vs baseline: 1.6535x; 1.2442x over previous
//
#include <hip/hip_runtime.h>

#define H    128
#define WP   130
#define BPF  516           // border pixels per face image
#define TBLN 3096          // 6 * 516

// Face order: back(0), down(1), front(2), left(3), right(4), top(5)
__constant__ int c_R[6][9] = {
  {-1,0,0,  0,1,0,  0,0,-1},
  { 1,0,0,  0,0,-1, 0,1,0 },
  { 1,0,0,  0,1,0,  0,0,1 },
  { 0,0,1,  0,1,0, -1,0,0 },
  { 0,0,-1, 0,1,0,  1,0,0 },
  { 1,0,0,  0,0,1,  0,-1,0},
};
// NEIGHBORS[face][side], side order: up(0), down(1), left(2), right(3)
__constant__ int c_conn[6][4] = {
  {5,1,4,3}, {2,0,3,4}, {5,1,3,4}, {5,1,0,2}, {5,1,2,0}, {0,2,3,4},
};

#define INV_FP (65.0f / 4128.0f)

// ---------- kernel A: build border table (3096 entries) ------------------
__global__ void __launch_bounds__(256)
border_table_kernel(int* __restrict__ tb_face, int4* __restrict__ tb_idx,
                    float4* __restrict__ tb_w) {
  int t = blockIdx.x * 256 + threadIdx.x;
  if (t >= TBLN) return;
  int face = t / BPF;
  int k    = t - face * BPF;

  int r, c;
  if (k < 130)      { r = 0;        c = k; }
  else if (k < 260) { r = WP - 1;   c = k - 130; }
  else if (k < 388) { r = k - 259;  c = 0; }
  else              { r = k - 387;  c = WP - 1; }

  int fs = -1;
  int4  idx = make_int4(0, 0, 0, 0);
  float4 w  = make_float4(0.f, 0.f, 0.f, 0.f);

  int cand[2]; int nc = 0;
  if (c == WP - 1) cand[nc++] = 3;
  if (c == 0)      cand[nc++] = 2;
  if (r == WP - 1) cand[nc++] = 1;
  if (r == 0)      cand[nc++] = 0;

  float uc = ((float)c - 64.5f) * INV_FP;
  float ur = ((float)r - 64.5f) * INV_FP;

  for (int kk = 0; kk < nc; ++kk) {
    int s  = cand[kk];
    int cf = c_conn[face][s];
    const int* Rc = c_R[cf];
    const int* Rf = c_R[face];
    float g[3];
    #pragma unroll
    for (int i = 0; i < 3; ++i) {
      float acc = 0.0f;
      #pragma unroll
      for (int j = 0; j < 3; ++j) {
        int rr = Rc[i*3+0]*Rf[j*3+0] + Rc[i*3+1]*Rf[j*3+1] + Rc[i*3+2]*Rf[j*3+2];
        float dj = (j == 0) ? uc : (j == 1) ? ur : 1.0f;
        acc += (float)rr * dj;
      }
      g[i] = acc;
    }
    float x = g[0] / g[2];
    float y = g[1] / g[2];
    if (fabsf(x) <= 1.01f && fabsf(y) <= 1.01f) {
      x = fminf(fmaxf(x, -1.0f), 1.0f);
      y = fminf(fmaxf(y, -1.0f), 1.0f);
      float xp = (x + 1.0f) * 0.5f * (float)(H - 1);
      float yp = (y + 1.0f) * 0.5f * (float)(H - 1);
      float x0 = floorf(xp), y0 = floorf(yp);
      float wx = xp - x0,    wy = yp - y0;
      int x0i = min(max((int)x0, 0), H - 1);
      int x1i = min(x0i + 1, H - 1);
      int y0i = min(max((int)y0, 0), H - 1);
      int y1i = min(y0i + 1, H - 1);
      fs  = cf;
      idx = make_int4(y0i * H + x0i, y0i * H + x1i, y1i * H + x0i, y1i * H + x1i);
      w   = make_float4((1.f - wx) * (1.f - wy), wx * (1.f - wy),
                        (1.f - wx) * wy,         wx * wy);
      break;
    }
  }
  tb_face[t] = fs;
  tb_idx[t]  = idx;
  tb_w[t]    = w;
}

// ---------- kernel B: fused bulk + edge ----------------------------------
// Bulk (blockIdx.x 0..15): half-row per 32-lane group. Lane l loads input
// quad A = in4[img*4096 + 32*hh + l] (dense, each input quad read once),
// neighbor quad via __shfl_down(.,1,32), selects by row parity, stores one
// aligned output quad (lanes 0..30). 1 dense 16B load + 1 dense 16B store
// per output quad = traffic floor.
// Edge (blockIdx.x == 16): 257 edge quads per image via border table.
__global__ void __launch_bounds__(256)
fused_kernel(const float* __restrict__ in, float4* __restrict__ out4,
             const int* __restrict__ tb_face,
             const int4* __restrict__ tb_idx,
             const float4* __restrict__ tb_w) {
  const unsigned bx  = blockIdx.x;
  const unsigned img = blockIdx.y;
  const unsigned u   = threadIdx.x;

  if (bx < 16u) {
    // ---- bulk path ----
    unsigned hh = (bx << 3) + (u >> 5);     // half index 0..127
    unsigned l  = u & 31u;                  // lane in 32-group
    unsigned g  = hh + 1u;                  // global half 1..128
    unsigned m  = g >> 1;                   // row-pair 0..64
    unsigned h  = g & 1u;                   // 1 = odd row of pair

    const float4* base = (const float4*)in + ((size_t)img << 12);
    float4 A = base[(hh << 5) + l];
    float bx0 = __shfl_down(A.x, 1, 32);
    float by0 = __shfl_down(A.y, 1, 32);
    float bz0 = __shfl_down(A.z, 1, 32);

    float4 o = h ? make_float4(A.y, A.z, A.w, bx0)
                 : make_float4(A.w, bx0, by0, bz0);
    if (l < 31u)
      out4[(size_t)img * 4225u + 65u * m + 1u + (h << 5) + l] = o;
  } else {
    // ---- edge path: 257 quads for this image ----
    unsigned n    = img >> 8;
    unsigned ch   = img & 255u;
    unsigned rep  = n / 6u;
    unsigned face = n - rep * 6u;

    for (unsigned k = u; k < 257u; k += 256u) {
      unsigned qk;
      if (k < 33u)       qk = k;                     // pair 0: q 0..32
      else if (k == 33u) qk = 64u;                   // pair 0: q 64
      else if (k == 34u) qk = 4160u;                 // pair 64: q 0
      else if (k < 68u)  qk = 4192u + (k - 35u);     // pair 64: q 32..64
      else {
        unsigned jj = k - 68u;                       // 0..188
        unsigned mm = 1u + jj / 3u;                  // 1..63
        unsigned w  = jj - 3u * (jj / 3u);           // 0,1,2
        qk = 65u * mm + ((w == 0u) ? 0u : (w == 1u) ? 32u : 64u);
      }

      unsigned p = qk << 2;
      unsigned r = p / 130u;
      unsigned c = p - r * 130u;
      float vals[4];
      #pragma unroll
      for (int jj = 0; jj < 4; ++jj) {
        float v;
        if ((r - 1u) < 128u && (c - 1u) < 128u) {
          v = in[(img << 14) + ((r - 1u) << 7) + (c - 1u)];
        } else {
          unsigned tk = (r == 0u)   ? c
                      : (r == 129u) ? (130u + c)
                      : (c == 0u)   ? (259u + r)
                      :               (387u + r);
          unsigned ti = face * (unsigned)BPF + tk;
          int fs = tb_face[ti];
          v = 0.0f;
          if (fs >= 0) {
            int4   id = tb_idx[ti];
            float4 w  = tb_w[ti];
            const float* s = in +
                ((size_t)(((rep * 6u + (unsigned)fs) << 8) + ch) << 14);
            v = w.x * s[id.x] + w.y * s[id.y] + w.z * s[id.z] + w.w * s[id.w];
          }
        }
        vals[jj] = v;
        if (++c == 130u) { c = 0u; ++r; }
      }
      out4[(size_t)img * 4225u + qk] =
          make_float4(vals[0], vals[1], vals[2], vals[3]);
    }
  }
}

// ---------- fallback (round-2 kernels) if d_ws unavailable ---------------
__global__ void __launch_bounds__(256)
interior_kernel(const float4* __restrict__ in4, float* __restrict__ out) {
  unsigned t = blockIdx.x * 256u + threadIdx.x;
  unsigned c4  = t & 31u;
  unsigned r   = (t >> 5) & 127u;
  unsigned img = t >> 12;
  float4 v = in4[t];
  unsigned o = img * 16900u + (r + 1u) * 130u + 1u + (c4 << 2);
  out[o] = v.x; out[o + 1] = v.y; out[o + 2] = v.z; out[o + 3] = v.w;
}

__global__ void __launch_bounds__(256)
border_kernel(const float* __restrict__ in, float* __restrict__ out) {
  unsigned tid = blockIdx.x * 256u + threadIdx.x;
  const unsigned total = 6144u * 516u;
  if (tid >= total) return;
  unsigned img = tid / 516u;
  unsigned k   = tid - img * 516u;
  int r, c;
  if (k < 130u)      { r = 0;               c = (int)k; }
  else if (k < 260u) { r = WP - 1;          c = (int)(k - 130u); }
  else if (k < 388u) { r = (int)(k - 259u); c = 0; }
  else               { r = (int)(k - 387u); c = WP - 1; }
  int n = (int)(img >> 8), ch = (int)(img & 255u);
  int face = n % 6, rep = n / 6;
  float v = 0.0f;
  int cand[2]; int nc = 0;
  if (c == WP - 1) cand[nc++] = 3;
  if (c == 0)      cand[nc++] = 2;
  if (r == WP - 1) cand[nc++] = 1;
  if (r == 0)      cand[nc++] = 0;
  float uc = ((float)c - 64.5f) * INV_FP;
  float ur = ((float)r - 64.5f) * INV_FP;
  for (int kk = 0; kk < nc; ++kk) {
    int s = cand[kk], cf = c_conn[face][s];
    const int* Rc = c_R[cf]; const int* Rf = c_R[face];
    float g[3];
    #pragma unroll
    for (int i = 0; i < 3; ++i) {
      float acc = 0.0f;
      #pragma unroll
      for (int j = 0; j < 3; ++j) {
        int rr = Rc[i*3+0]*Rf[j*3+0] + Rc[i*3+1]*Rf[j*3+1] + Rc[i*3+2]*Rf[j*3+2];
        float dj = (j == 0) ? uc : (j == 1) ? ur : 1.0f;
        acc += (float)rr * dj;
      }
      g[i] = acc;
    }
    float x = g[0] / g[2], y = g[1] / g[2];
    if (fabsf(x) <= 1.01f && fabsf(y) <= 1.01f) {
      x = fminf(fmaxf(x, -1.0f), 1.0f);
      y = fminf(fmaxf(y, -1.0f), 1.0f);
      const float* src = in + ((size_t)((rep * 6 + cf) * 256 + ch)) * H * H;
      float xp = (x + 1.0f) * 0.5f * (float)(H - 1);
      float yp = (y + 1.0f) * 0.5f * (float)(H - 1);
      float x0 = floorf(xp), y0 = floorf(yp);
      float wx = xp - x0, wy = yp - y0;
      int x0i = min(max((int)x0, 0), H - 1);
      int x1i = min(x0i + 1, H - 1);
      int y0i = min(max((int)y0, 0), H - 1);
      int y1i = min(y0i + 1, H - 1);
      v = src[y0i*H+x0i]*(1.f-wx)*(1.f-wy) + src[y0i*H+x1i]*wx*(1.f-wy)
        + src[y1i*H+x0i]*(1.f-wx)*wy       + src[y1i*H+x1i]*wx*wy;
      break;
    }
  }
  out[(unsigned)img * 16900u + (unsigned)r * 130u + (unsigned)c] = v;
}

extern "C" void kernel_launch(void* const* d_in, const int* in_sizes, int n_in,
                              void* d_out, int out_size, void* d_ws, size_t ws_size,
                              hipStream_t stream) {
  (void)in_sizes; (void)n_in; (void)out_size;
  const float* in = (const float*)d_in[0];
  float* out = (float*)d_out;

  const size_t need = (size_t)TBLN * (4 + 16 + 16);   // 111,456 B
  if (d_ws != nullptr && ws_size >= need) {
    int*    tb_face = (int*)d_ws;
    int4*   tb_idx  = (int4*)(tb_face + TBLN);
    float4* tb_w    = (float4*)(tb_idx + TBLN);
    border_table_kernel<<<(TBLN + 255) / 256, 256, 0, stream>>>(tb_face, tb_idx, tb_w);

    dim3 grid(17, 6144);   // x 0..15 bulk, x==16 edge
    fused_kernel<<<grid, 256, 0, stream>>>(in, (float4*)out,
                                           tb_face, tb_idx, tb_w);
  } else {
    interior_kernel<<<98304, 256, 0, stream>>>((const float4*)in, out);
    const unsigned btotal = 6144u * 516u;
    border_kernel<<<(btotal + 255u) / 256u, 256, 0, stream>>>(in, out);
  }
}